// Round 7
// baseline (306.308 us; speedup 1.0000x reference)
//
#include <hip/hip_runtime.h>
#include <math.h>

#define B_ 32
#define N_ 64
#define K_ 128
#define NPAIR (B_*N_*N_)
#define NTRI 2080              // 64*65/2 pairs (i<=j) per batch
#define GEOM_BLOCKS 260        // 32*2080/256
#define PREP_COUNT 741376
#define PREP_BLOCKS 2896       // 741376/256

typedef __attribute__((ext_vector_type(8))) short short8;
typedef __attribute__((ext_vector_type(8))) __bf16 bf16x8;
typedef __attribute__((ext_vector_type(4))) float floatx4;

__device__ __forceinline__ float silu_f(float x) {
    float e = __builtin_amdgcn_exp2f(-1.442695040888963f * x);
    return x * __builtin_amdgcn_rcpf(1.0f + e);
}
__device__ __forceinline__ float4 ld4(const float* p) { return *(const float4*)p; }

__device__ __forceinline__ short f2bf(float x) {
    union { float f; unsigned u; } v; v.f = x;
    unsigned r = (v.u + 0x7FFFu + ((v.u >> 16) & 1u)) >> 16;
    return (short)r;
}
__device__ __forceinline__ float bf2f(short s) {
    union { unsigned u; float f; } v;
    v.u = ((unsigned)(unsigned short)s) << 16;
    return v.f;
}
__device__ __forceinline__ bf16x8 ld_frag(const short* p) {
    short8 r = *(const short8*)p;
    return __builtin_bit_cast(bf16x8, r);
}

// triangular decode: t in [0,2080) -> (i,j), i<=j
__device__ __forceinline__ int2 tri_decode(int t) {
    float f = (129.0f - sqrtf((float)(16641 - 8*t))) * 0.5f;
    int i = (int)f;
    int off = 64*i - (i*(i-1))/2;
    if (off > t) { i--; off = 64*i - (i*(i-1))/2; }
    else {
        int offn = 64*(i+1) - ((i+1)*i)/2;
        if (offn <= t) { i = i+1; off = offn; }
    }
    return make_int2(i, i + (t - off));
}

// ---------------------------------------------------------------------------
// pre: fused geom (triangular, hw sin/cos) + weight prep.
// prep bf16 sections (short offsets):
//  0       r1w1T  [64][64]
//  4096    r1w2T  [64][64]
//  8192    r2w1T  [64][64]
//  12288   r2w2T  [64][64]
//  16384   w3T2   [256col][64k]  (r2w3 transposed; [32768,40960) zero)
//  40960   wT0    [512][704]  zero pad k>=641
//  401408  wT1    [512][512]
//  663552  w0T1   [64][32]    zero pad k>=8
//  665600  w0T2   [64][32]
//  667648  w3T1   [384][64]   r1w3[h][col]*wemb[col&127]/16
//  692224  lT     [128][384]  stacked [l0; l2; l1]
//  741376  end
// ---------------------------------------------------------------------------
__global__ __launch_bounds__(256) void pre_kernel(
    const float* __restrict__ pos, const float* __restrict__ cell,
    short* __restrict__ radbf, float* __restrict__ Y1, float* __restrict__ Y2,
    float* __restrict__ maskf,
    const float* __restrict__ r1w0, const float* __restrict__ r1w1,
    const float* __restrict__ r1w2, const float* __restrict__ r1w3,
    const float* __restrict__ r2w0, const float* __restrict__ r2w1,
    const float* __restrict__ r2w2, const float* __restrict__ r2w3,
    const float* __restrict__ mw0, const float* __restrict__ mw1,
    const float* __restrict__ wemb,
    const float* __restrict__ l0, const float* __restrict__ l1,
    const float* __restrict__ l2, short* __restrict__ dst)
{
    int t = threadIdx.x;
    if (blockIdx.x < GEOM_BLOCKS) {
        int gt = blockIdx.x * 256 + t;
        int b = gt / NTRI;
        int tt = gt - b*NTRI;
        int2 ij = tri_decode(tt);
        int i = ij.x, j = ij.y;
        const float* pi = pos + (size_t)(b*N_ + i)*3;
        const float* pj = pos + (size_t)(b*N_ + j)*3;
        float d0 = pi[0]-pj[0], d1 = pi[1]-pj[1], d2 = pi[2]-pj[2];
        d0 -= rintf(d0); d1 -= rintf(d1); d2 -= rintf(d2);
        const float* C = cell + b*9;
        float dc0 = d0*C[0] + d1*C[3] + d2*C[6];
        float dc1 = d0*C[1] + d1*C[4] + d2*C[7];
        float dc2 = d0*C[2] + d1*C[5] + d2*C[8];
        float r2 = fmaxf(dc0*dc0 + dc1*dc1 + dc2*dc2, 1e-12f);
        float r = sqrtf(r2);
        bool m = (r < 5.0f) && (i != j);
        float mf = m ? 1.0f : 0.0f;
        float rs = m ? r : 1.0f;
        float inv_rs = __builtin_amdgcn_rcpf(rs);
        inv_rs = inv_rs * (2.0f - rs*inv_rs);
        float x = dc0*inv_rs*mf, y = dc1*inv_rs*mf, z = dc2*inv_rs*mf;
        float u = r * 0.2f;
        float u2 = u*u, u4 = u2*u2, u5 = u4*u;
        float fc = 1.0f - 21.0f*u5 + 35.0f*u5*u - 15.0f*u5*u2;
        fc = (u < 1.0f) ? fc : 0.0f;
        float pref = 0.6324555320336759f * inv_rs * (fc * mf);
        float rev = 0.1f * rs;
        float sw = __builtin_amdgcn_sinf(rev);
        float cw = __builtin_amdgcn_cosf(rev);
        float c2 = 2.0f * cw;
        short8 sv;
        float sp = 0.f, s = sw;
        #pragma unroll
        for (int n = 0; n < 8; n++) {
            sv[n] = f2bf(pref * s);
            float ns = c2*s - sp;
            sp = s; s = ns;
        }
        size_t pu = ((size_t)b*64 + i)*64 + j;
        size_t pl = ((size_t)b*64 + j)*64 + i;
        *(short8*)&radbf[pu*8] = sv;
        const float s3  = 1.7320508075688772f;
        const float s5  = 2.23606797749979f;
        const float s15 = 3.872983346207417f;
        float y1x = s3*x, y1y = s3*y, y1z = s3*z;
        Y1[pu*3+0] = y1x; Y1[pu*3+1] = y1y; Y1[pu*3+2] = y1z;
        Y1[pl*3+0] = -y1x; Y1[pl*3+1] = -y1y; Y1[pl*3+2] = -y1z;
        float q0 = s15*x*y, q1 = s15*y*z, q2 = 0.5f*s5*(3.0f*z*z - 1.0f);
        float q3 = s15*x*z, q4 = 0.5f*s15*(x*x - y*y);
        Y2[pu*5+0]=q0; Y2[pu*5+1]=q1; Y2[pu*5+2]=q2; Y2[pu*5+3]=q3; Y2[pu*5+4]=q4;
        Y2[pl*5+0]=q0; Y2[pl*5+1]=q1; Y2[pl*5+2]=q2; Y2[pl*5+3]=q3; Y2[pl*5+4]=q4;
        maskf[pu] = mf; maskf[pl] = mf;
        return;
    }
    int idx = (blockIdx.x - GEOM_BLOCKS) * 256 + t;
    if (idx >= PREP_COUNT) return;
    short v;
    if (idx < 4096) {
        int n = idx >> 6, k = idx & 63; v = f2bf(r1w1[k*64 + n]);
    } else if (idx < 8192) {
        int i = idx - 4096; int n = i >> 6, k = i & 63; v = f2bf(r1w2[k*64 + n]);
    } else if (idx < 12288) {
        int i = idx - 8192; int n = i >> 6, k = i & 63; v = f2bf(r2w1[k*64 + n]);
    } else if (idx < 16384) {
        int i = idx - 12288; int n = i >> 6, k = i & 63; v = f2bf(r2w2[k*64 + n]);
    } else if (idx < 40960) {
        int i = idx - 16384;
        v = (i < 16384) ? f2bf(r2w3[(i & 63)*256 + (i >> 6)]) : (short)0;
    } else if (idx < 401408) {
        int i = idx - 40960; int n = i / 704, k = i - n*704;
        v = (k < 641) ? f2bf(mw0[(size_t)k*512 + n]) : (short)0;
    } else if (idx < 663552) {
        int i = idx - 401408; int n = i >> 9, k = i & 511;
        v = f2bf(mw1[(size_t)k*512 + n]);
    } else if (idx < 665600) {
        int i = idx - 663552; int n = i >> 5, k = i & 31;
        v = (k < 8) ? f2bf(r1w0[k*64 + n]) : (short)0;
    } else if (idx < 667648) {
        int i = idx - 665600; int n = i >> 5, k = i & 31;
        v = (k < 8) ? f2bf(r2w0[k*64 + n]) : (short)0;
    } else if (idx < 692224) {
        int i = idx - 667648; int col = i >> 6, h = i & 63;
        v = f2bf(r1w3[h*384 + col] * wemb[col & 127] * 0.0625f);
    } else {
        int i = idx - 692224; int n = i / 384, k = i - n*384;
        float f;
        if (k < 128)       f = l0[k*128 + n];
        else if (k < 256)  f = l2[(k-128)*128 + n];
        else               f = l1[(k-256)*128 + n];
        v = f2bf(f);
    }
    dst[idx] = v;
}

// ---------------------------------------------------------------------------
// bigmlp: triangular pair-parallel radial MLPs (both nets).
// ---------------------------------------------------------------------------
__global__ __launch_bounds__(256) void bigmlp_kernel(
    const short* __restrict__ radbf,
    const short* __restrict__ w0T1, const float* __restrict__ b01,
    const short* __restrict__ w1T1, const float* __restrict__ b11,
    const short* __restrict__ w2T1, const float* __restrict__ b21,
    short* __restrict__ hc1,
    const short* __restrict__ w0T2, const float* __restrict__ b02,
    const short* __restrict__ w1T2, const float* __restrict__ b12,
    const short* __restrict__ w2T2, const float* __restrict__ b22,
    short* __restrict__ hc2)
{
    __shared__ short radB[128*40];
    __shared__ short actA[128*72];
    __shared__ short actB[128*72];
    __shared__ int prs[128];
    int t = threadIdx.x;
    int wv = t >> 6, lane = t & 63, qd = lane >> 4, nn = lane & 15;
    int bb = blockIdx.x / 17;
    int chunk = blockIdx.x - bb*17;

    if (t < 128) {
        int tt0 = chunk*128 + t;
        uint4 z = {0,0,0,0};
        uint4 rv = z;
        int pr = -1;
        if (tt0 < NTRI) {
            int2 ij = tri_decode(tt0);
            pr = (ij.x << 8) | ij.y;
            size_t pu = ((size_t)bb*64 + ij.x)*64 + ij.y;
            rv = *(const uint4*)&radbf[pu*8];
        }
        prs[t] = pr;
        *(uint4*)&radB[t*40]      = rv;
        *(uint4*)&radB[t*40 + 8]  = z;
        *(uint4*)&radB[t*40 + 16] = z;
        *(uint4*)&radB[t*40 + 24] = z;
        *(uint4*)&radB[t*40 + 32] = z;
    }
    __syncthreads();

    const short* w0Ts[2] = {w0T1, w0T2};
    const short* w1Ts[2] = {w1T1, w1T2};
    const short* w2Ts[2] = {w2T1, w2T2};
    const float* b0s[2]  = {b01, b02};
    const float* b1s[2]  = {b11, b12};
    const float* b2s[2]  = {b21, b22};
    short* hcs[2] = {hc1, hc2};

    for (int net = 0; net < 2; net++) {
        const short* w0T = w0Ts[net];
        const short* w1T = w1Ts[net];
        const short* w2T = w2Ts[net];
        const float* b0 = b0s[net];
        const float* b1 = b1s[net];
        const float* b2 = b2s[net];
        short* hc = hcs[net];
        #pragma unroll
        for (int ms = 0; ms < 2; ms++) {
            int r0 = wv*32 + ms*16;
            bf16x8 a = ld_frag(&radB[(r0 + nn)*40 + qd*8]);
            #pragma unroll
            for (int tt = 0; tt < 4; tt++) {
                floatx4 acc = (floatx4){0.f,0.f,0.f,0.f};
                bf16x8 bb_ = ld_frag(&w0T[(tt*16 + nn)*32 + qd*8]);
                acc = __builtin_amdgcn_mfma_f32_16x16x32_bf16(a, bb_, acc, 0, 0, 0);
                int col = tt*16 + nn;
                float bv = b0[col];
                #pragma unroll
                for (int i = 0; i < 4; i++)
                    actA[(r0 + qd*4 + i)*72 + col] = f2bf(silu_f(acc[i] + bv));
            }
        }
        __syncthreads();
        #pragma unroll
        for (int ms = 0; ms < 2; ms++) {
            int r0 = wv*32 + ms*16;
            bf16x8 a0 = ld_frag(&actA[(r0 + nn)*72 + qd*8]);
            bf16x8 a1 = ld_frag(&actA[(r0 + nn)*72 + 32 + qd*8]);
            #pragma unroll
            for (int tt = 0; tt < 4; tt++) {
                floatx4 acc = (floatx4){0.f,0.f,0.f,0.f};
                bf16x8 b0f = ld_frag(&w1T[(tt*16 + nn)*64 + qd*8]);
                bf16x8 b1f = ld_frag(&w1T[(tt*16 + nn)*64 + 32 + qd*8]);
                acc = __builtin_amdgcn_mfma_f32_16x16x32_bf16(a0, b0f, acc, 0, 0, 0);
                acc = __builtin_amdgcn_mfma_f32_16x16x32_bf16(a1, b1f, acc, 0, 0, 0);
                int col = tt*16 + nn;
                float bv = b1[col];
                #pragma unroll
                for (int i = 0; i < 4; i++)
                    actB[(r0 + qd*4 + i)*72 + col] = f2bf(silu_f(acc[i] + bv));
            }
        }
        __syncthreads();
        #pragma unroll
        for (int ms = 0; ms < 2; ms++) {
            int r0 = wv*32 + ms*16;
            bf16x8 a0 = ld_frag(&actB[(r0 + nn)*72 + qd*8]);
            bf16x8 a1 = ld_frag(&actB[(r0 + nn)*72 + 32 + qd*8]);
            #pragma unroll
            for (int tt = 0; tt < 4; tt++) {
                floatx4 acc = (floatx4){0.f,0.f,0.f,0.f};
                bf16x8 b0f = ld_frag(&w2T[(tt*16 + nn)*64 + qd*8]);
                bf16x8 b1f = ld_frag(&w2T[(tt*16 + nn)*64 + 32 + qd*8]);
                acc = __builtin_amdgcn_mfma_f32_16x16x32_bf16(a0, b0f, acc, 0, 0, 0);
                acc = __builtin_amdgcn_mfma_f32_16x16x32_bf16(a1, b1f, acc, 0, 0, 0);
                int col = tt*16 + nn;
                float bv = b2[col];
                #pragma unroll
                for (int i = 0; i < 4; i++) {
                    int pr = prs[r0 + qd*4 + i];
                    if (pr >= 0) {
                        short val = f2bf(silu_f(acc[i] + bv));
                        int pi = pr >> 8, pj = pr & 255;
                        size_t base = (size_t)bb*4096;
                        hc[(base + pi*64 + pj)*64 + col] = val;
                        if (pi != pj)
                            hc[(base + pj*64 + pi)*64 + col] = val;
                    }
                }
            }
        }
        __syncthreads();
    }
}

// ---------------------------------------------------------------------------
// msg1: per-node pass-1 messages; 5 barriers (merged zero/fill phases).
// ---------------------------------------------------------------------------
__global__ __launch_bounds__(256) void msg1_kernel(
    const short* __restrict__ hc1, const float* __restrict__ Y1g,
    const float* __restrict__ Y2g, const float* __restrict__ maskg,
    const float* __restrict__ wemb, const float* __restrict__ b3,
    const short* __restrict__ w3T, const short* __restrict__ lT,
    const float* __restrict__ timeg,
    short* __restrict__ h1bf, float* __restrict__ v1g, short* __restrict__ featsb)
{
    __shared__ __align__(16) char pool[19008];
    short* hcT  = (short*)pool;              // [64h][72j], bytes [0,9216)
    short* A2   = (short*)pool;              // [16][392] shorts = bytes [0,12544)
    short* YmB  = (short*)(pool + 9216);     // [16][72]
    short* GB   = (short*)(pool + 11520);    // [16][72] bytes [11520,13824)
    float* msgF = (float*)(pool + 13824);    // [9*128]
    float* qF   = (float*)(pool + 18432);    // [128]
    float* SY   = (float*)(pool + 18944);    // [16]

    int t = threadIdx.x;
    int wv = t >> 6, lane = t & 63, qd = lane >> 4, nn = lane & 15;
    int node = blockIdx.x;
    int b = node >> 6;
    size_t pbase = (size_t)node * 64;

    // P0: hcT stage + YmB zero rows 9..15 + YmB fill rows 0..8
    for (int idx = t; idx < 512; idx += 256) {
        int j = idx >> 3, h0 = (idx & 7)*8;
        short8 v = *(const short8*)&hc1[((size_t)node*64 + j)*64 + h0];
        #pragma unroll
        for (int q = 0; q < 8; q++) hcT[(h0 + q)*72 + j] = v[q];
    }
    for (int idx = t; idx < 504; idx += 256) YmB[648 + idx] = 0;
    if (t < 64) {
        int j = t;
        float mf = maskg[pbase + j];
        YmB[j] = f2bf(mf);
        #pragma unroll
        for (int m = 0; m < 3; m++) YmB[(1+m)*72 + j] = f2bf(Y1g[(pbase+j)*3 + m] * mf);
        #pragma unroll
        for (int m = 0; m < 5; m++) YmB[(4+m)*72 + j] = f2bf(Y2g[(pbase+j)*5 + m] * mf);
    }
    __syncthreads();
    // P1: SY + G GEMM
    if (t < 16) {
        float acc = 0.f;
        if (t < 9) for (int j = 0; j < 64; j++) acc += bf2f(YmB[t*72 + j]);
        SY[t] = acc;
    }
    {
        floatx4 accG = (floatx4){0.f,0.f,0.f,0.f};
        #pragma unroll
        for (int ks = 0; ks < 64; ks += 32) {
            bf16x8 a = ld_frag(&YmB[nn*72 + ks + qd*8]);
            bf16x8 bfr = ld_frag(&hcT[(wv*16 + nn)*72 + ks + qd*8]);
            accG = __builtin_amdgcn_mfma_f32_16x16x32_bf16(a, bfr, accG, 0, 0, 0);
        }
        #pragma unroll
        for (int i = 0; i < 4; i++)
            GB[(qd*4 + i)*72 + wv*16 + nn] = f2bf(accG[i]);
    }
    __syncthreads();
    // P2: msg GEMM + zero A2 shorts [0,5760) (hcT/YmB dead; GB untouched)
    {
        short8 z8 = {0,0,0,0,0,0,0,0};
        for (int idx = t; idx < 720; idx += 256) *(short8*)&A2[idx*8] = z8;
        bf16x8 a0f = ld_frag(&GB[nn*72 + 0  + qd*8]);
        bf16x8 a1f = ld_frag(&GB[nn*72 + 32 + qd*8]);
        #pragma unroll
        for (int tl = 0; tl < 6; tl++) {
            int col0 = (wv*6 + tl)*16;
            floatx4 acc = (floatx4){0.f,0.f,0.f,0.f};
            bf16x8 b0f = ld_frag(&w3T[(col0 + nn)*64 + 0  + qd*8]);
            bf16x8 b1f = ld_frag(&w3T[(col0 + nn)*64 + 32 + qd*8]);
            acc = __builtin_amdgcn_mfma_f32_16x16x32_bf16(a0f, b0f, acc, 0, 0, 0);
            acc = __builtin_amdgcn_mfma_f32_16x16x32_bf16(a1f, b1f, acc, 0, 0, 0);
            int col = col0 + nn;
            int csec = col >> 7, k = col & 127;
            #pragma unroll
            for (int i = 0; i < 4; i++) {
                int m = qd*4 + i;
                bool valid = (csec == 0) ? (m == 0)
                           : (csec == 1) ? (m >= 1 && m <= 3)
                                         : (m >= 4 && m <= 8);
                if (valid)
                    msgF[m*128 + k] = acc[i] + SY[m]*b3[col]*wemb[k]*0.0625f;
            }
        }
    }
    __syncthreads();
    // P3: q + zero A2 shorts [5760,6272) (GB dead)
    A2[5760 + t] = 0;
    A2[6016 + t] = 0;
    if (t < 128) {
        float acc = 0.f;
        #pragma unroll
        for (int m = 4; m < 9; m++) { float v = msgF[m*128 + t]; acc += v*v; }
        qF[t] = acc;
    }
    __syncthreads();
    // P4: fill A2: row0 = [msg0 | q]; rows1-3 cols 256..383 = msg_m
    A2[t] = (t < 128) ? f2bf(msgF[t]) : f2bf(qF[t - 128]);
    if (t < 128) {
        #pragma unroll
        for (int m = 1; m <= 3; m++)
            A2[m*392 + 256 + t] = f2bf(msgF[m*128 + t]);
    }
    __syncthreads();
    // P5: s1v1 GEMM
    #pragma unroll
    for (int tt = 0; tt < 2; tt++) {
        int col = (wv*2 + tt)*16 + nn;
        floatx4 acc = (floatx4){0.f,0.f,0.f,0.f};
        #pragma unroll
        for (int ks = 0; ks < 384; ks += 32) {
            bf16x8 a = ld_frag(&A2[nn*392 + ks + qd*8]);
            bf16x8 bfr = ld_frag(&lT[(size_t)col*384 + ks + qd*8]);
            acc = __builtin_amdgcn_mfma_f32_16x16x32_bf16(a, bfr, acc, 0, 0, 0);
        }
        if (qd == 0) {
            float s1 = acc[0];
            featsb[(size_t)node*704 + col] = f2bf(s1);
            h1bf[(size_t)node*128 + col] = f2bf(silu_f(s1));
            #pragma unroll
            for (int i = 1; i < 4; i++) {
                float v = acc[i];
                v1g[(size_t)node*384 + (i-1)*128 + col] = v;
                featsb[(size_t)node*704 + 128 + (i-1)*128 + col] = f2bf(v);
            }
        }
    }
    if (t == 0) featsb[(size_t)node*704 + 640] = f2bf(timeg[b]);
    if (t < 63) featsb[(size_t)node*704 + 641 + t] = 0;
}

// ---------------------------------------------------------------------------
// msg2h: grid (2048, 2). Half 0: cols 0-127 vs h1; half 1: cols 128-255 vs
// inv. 27.4 KB LDS -> 5 blocks/CU. Writes fp32 partial msgp{A,B}.
// ---------------------------------------------------------------------------
__global__ __launch_bounds__(256) void msg2h_kernel(
    const short* __restrict__ hc2, const float* __restrict__ Y1g,
    const float* __restrict__ maskg, const short* __restrict__ w3T2,
    const float* __restrict__ b3,
    const short* __restrict__ h1bf, const float* __restrict__ v1g,
    float* __restrict__ msgpA, float* __restrict__ msgpB)
{
    __shared__ __align__(16) char pool[27648];
    short* hc2e  = (short*)pool;              // [64][72]
    short* srcB  = (short*)(pool + 9216);     // [64][136]
    float* mask_s= (float*)(pool + 26624);    // [64]
    float* msgab = (float*)(pool + 26880);    // [128]

    int t = threadIdx.x;
    int wv = t >> 6, lane = t & 63, qd = lane >> 4, nn = lane & 15;
    int node = blockIdx.x;
    int half = blockIdx.y;
    int b = node >> 6;
    size_t pbase = (size_t)node * 64;

    // P0: stage everything
    if (t < 64) mask_s[t] = maskg[pbase + t];
    for (int idx = t; idx < 512; idx += 256) {
        int j = idx >> 3, h0 = (idx & 7)*8;
        short8 v = *(const short8*)&hc2[((size_t)node*64 + j)*64 + h0];
        float mf = maskg[pbase + j];
        if (mf == 0.f) { short8 z8 = {0,0,0,0,0,0,0,0}; v = z8; }
        *(short8*)&hc2e[j*72 + h0] = v;
    }
    if (half == 0) {
        for (int idx = t; idx < 1024; idx += 256) {
            int j = idx >> 4, k0 = (idx & 15)*8;
            *(uint4*)&srcB[j*136 + k0] = *(const uint4*)&h1bf[((size_t)b*64 + j)*128 + k0];
        }
    } else {
        for (int idx = t; idx < 2048; idx += 256) {
            int j = idx >> 5, kq = (idx & 31)*4;
            const float* vb = &v1g[((size_t)b*64 + j)*384 + kq];
            float4 vx = ld4(vb), vy = ld4(vb + 128), vz = ld4(vb + 256);
            const float* yp = &Y1g[(pbase + j)*3];
            float yx = yp[0], yy = yp[1], yz = yp[2];
            srcB[j*136 + kq + 0] = f2bf(yx*vx.x + yy*vy.x + yz*vz.x);
            srcB[j*136 + kq + 1] = f2bf(yx*vx.y + yy*vy.y + yz*vz.y);
            srcB[j*136 + kq + 2] = f2bf(yx*vx.z + yy*vy.z + yz*vz.z);
            srcB[j*136 + kq + 3] = f2bf(yx*vx.w + yy*vy.w + yz*vz.w);
        }
    }
    if (t < 128) msgab[t] = 0.f;
    __syncthreads();
    // P1: GEMM (K=64) + epilogue
    {
        bf16x8 a0 = ld_frag(&hc2e[(wv*16 + nn)*72 + qd*8]);
        bf16x8 a1 = ld_frag(&hc2e[(wv*16 + nn)*72 + 32 + qd*8]);
        int gbase = half*2;
        for (int g = gbase; g < gbase + 2; g++) {
            #pragma unroll
            for (int tt = 0; tt < 4; tt++) {
                int col0 = g*64 + tt*16;
                int col = col0 + nn;
                floatx4 acc = (floatx4){0.f,0.f,0.f,0.f};
                bf16x8 b0f = ld_frag(&w3T2[(size_t)col*64 + qd*8]);
                bf16x8 b1f = ld_frag(&w3T2[(size_t)col*64 + 32 + qd*8]);
                acc = __builtin_amdgcn_mfma_f32_16x16x32_bf16(a0, b0f, acc, 0, 0, 0);
                acc = __builtin_amdgcn_mfma_f32_16x16x32_bf16(a1, b1f, acc, 0, 0, 0);
                int k = col & 127;
                float bb = b3[col];
                float p = 0.f;
                #pragma unroll
                for (int i = 0; i < 4; i++) {
                    int j = wv*16 + qd*4 + i;
                    float we = acc[i] + bb*mask_s[j];
                    p += we * bf2f(srcB[j*136 + k]);
                }
                p += __shfl_xor(p, 16);
                p += __shfl_xor(p, 32);
                if (qd == 0) atomicAdd(&msgab[k], p);
            }
        }
    }
    __syncthreads();
    // P2: write partial
    if (t < 128) {
        float* dst = (half == 0) ? msgpA : msgpB;
        dst[(size_t)node*128 + t] = msgab[t];
    }
}

// ---------------------------------------------------------------------------
// s2: featsb[:,512:640] = ((msgpA+msgpB)/16) @ mix2. One block per node.
// ---------------------------------------------------------------------------
__global__ __launch_bounds__(128) void s2_kernel(
    const float* __restrict__ msgpA, const float* __restrict__ msgpB,
    const float* __restrict__ mix2, short* __restrict__ featsb)
{
    __shared__ float s[128];
    int t = threadIdx.x;
    int node = blockIdx.x;
    s[t] = msgpA[(size_t)node*128 + t] + msgpB[(size_t)node*128 + t];
    __syncthreads();
    float acc = 0.f;
    for (int k = 0; k < 128; k++) acc += s[k] * mix2[k*128 + t];
    featsb[(size_t)node*704 + 512 + t] = f2bf(acc * 0.0625f);
}

// ---------------------------------------------------------------------------
// gemm_part: stage-less, barrier-free split-K partial GEMM.
// ---------------------------------------------------------------------------
__global__ __launch_bounds__(256) void gemm_part_kernel(
    const short* __restrict__ A, int lda,
    const short* __restrict__ BT, int ldb,
    int ngran, int nsplit, float* __restrict__ Cp)
{
    int t = threadIdx.x;
    int wv = t >> 6, lane = t & 63, qd = lane >> 4, nn = lane & 15;
    int m0 = blockIdx.x * 64, n0 = blockIdx.y * 64, z = blockIdx.z;
    int g0 = (z*ngran)/nsplit, g1 = ((z+1)*ngran)/nsplit;
    floatx4 acc[4];
    #pragma unroll
    for (int tt = 0; tt < 4; tt++) acc[tt] = (floatx4){0.f,0.f,0.f,0.f};
    int row = wv*16 + nn;
    for (int g = g0; g < g1; g++) {
        int k = g*32;
        bf16x8 a = ld_frag(&A[(size_t)(m0 + row)*lda + k + qd*8]);
        #pragma unroll
        for (int tt = 0; tt < 4; tt++) {
            bf16x8 bb = ld_frag(&BT[(size_t)(n0 + tt*16 + nn)*ldb + k + qd*8]);
            acc[tt] = __builtin_amdgcn_mfma_f32_16x16x32_bf16(a, bb, acc[tt], 0, 0, 0);
        }
    }
    float* out = Cp + (size_t)z*2048*512;
    #pragma unroll
    for (int tt = 0; tt < 4; tt++) {
        int n = n0 + tt*16 + nn;
        #pragma unroll
        for (int i = 0; i < 4; i++)
            out[(size_t)(m0 + wv*16 + qd*4 + i)*512 + n] = acc[tt][i];
    }
}

__global__ __launch_bounds__(256) void combine_kernel(
    const float* __restrict__ Cp, const float* __restrict__ bias,
    short* __restrict__ out)
{
    int idx = (blockIdx.x * 256 + threadIdx.x) * 4;
    int n = idx & 511;
    float4 s = ld4(&Cp[idx]);
    #pragma unroll
    for (int z = 1; z < 4; z++) {
        float4 p = ld4(&Cp[(size_t)z*1048576 + idx]);
        s.x += p.x; s.y += p.y; s.z += p.z; s.w += p.w;
    }
    float4 bv = ld4(&bias[n]);
    short4 o;
    o.x = f2bf(fmaxf(s.x + bv.x, 0.f));
    o.y = f2bf(fmaxf(s.y + bv.y, 0.f));
    o.z = f2bf(fmaxf(s.z + bv.z, 0.f));
    o.w = f2bf(fmaxf(s.w + bv.w, 0.f));
    *(short4*)&out[idx] = o;
}

__global__ __launch_bounds__(64) void final3_kernel(
    const short* __restrict__ H, const float* __restrict__ w2,
    const float* __restrict__ b2, float* __restrict__ out)
{
    int node = blockIdx.x, lane = threadIdx.x;
    float a0 = 0.f, a1 = 0.f, a2 = 0.f;
    #pragma unroll
    for (int r = 0; r < 8; r++) {
        int k = r*64 + lane;
        float h = bf2f(H[(size_t)node*512 + k]);
        a0 += h * w2[k*3 + 0];
        a1 += h * w2[k*3 + 1];
        a2 += h * w2[k*3 + 2];
    }
    #pragma unroll
    for (int off = 32; off > 0; off >>= 1) {
        a0 += __shfl_down(a0, off);
        a1 += __shfl_down(a1, off);
        a2 += __shfl_down(a2, off);
    }
    if (lane == 0) {
        out[(size_t)node*3 + 0] = a0 + b2[0];
        out[(size_t)node*3 + 1] = a1 + b2[1];
        out[(size_t)node*3 + 2] = a2 + b2[2];
    }
}

extern "C" void kernel_launch(void* const* d_in, const int* in_sizes, int n_in,
                              void* d_out, int out_size, void* d_ws, size_t ws_size,
                              hipStream_t stream) {
    const float* pos   = (const float*)d_in[0];
    const float* timeg = (const float*)d_in[1];
    const float* cell  = (const float*)d_in[2];
    const float* wemb  = (const float*)d_in[3];
    const float* r1w0  = (const float*)d_in[4];
    const float* r1b0  = (const float*)d_in[5];
    const float* r1w1  = (const float*)d_in[6];
    const float* r1b1  = (const float*)d_in[7];
    const float* r1w2  = (const float*)d_in[8];
    const float* r1b2  = (const float*)d_in[9];
    const float* r1w3  = (const float*)d_in[10];
    const float* r1b3  = (const float*)d_in[11];
    const float* l0    = (const float*)d_in[12];
    const float* l1    = (const float*)d_in[13];
    const float* l2    = (const float*)d_in[14];
    const float* r2w0  = (const float*)d_in[15];
    const float* r2b0  = (const float*)d_in[16];
    const float* r2w1  = (const float*)d_in[17];
    const float* r2b1  = (const float*)d_in[18];
    const float* r2w2  = (const float*)d_in[19];
    const float* r2b2  = (const float*)d_in[20];
    const float* r2w3  = (const float*)d_in[21];
    const float* r2b3  = (const float*)d_in[22];
    const float* mix2  = (const float*)d_in[23];
    const float* mw0   = (const float*)d_in[24];
    const float* mb0   = (const float*)d_in[25];
    const float* mw1   = (const float*)d_in[26];
    const float* mb1   = (const float*)d_in[27];
    const float* mw2   = (const float*)d_in[28];
    const float* mb2   = (const float*)d_in[29];

    float* ws = (float*)d_ws;
    short* radbf  = (short*)ws;                          // NPAIR*8 sh (dead after bigmlp)
    float* Y1     = ws + 524288;
    float* Y2     = ws + 917504;
    float* maskf  = ws + 1572864;
    float* v1     = ws + 1703936;
    short* featsb = (short*)(ws + 2490368);
    short* prep   = (short*)(ws + 3211264);
    short* hc1    = (short*)(ws + 3590144);
    short* hc2    = (short*)(ws + 7784448);
    short* h1bf   = (short*)(ws + 11978752);

    short* w1T_1  = prep;
    short* w2T_1  = prep + 4096;
    short* w1T_2  = prep + 8192;
    short* w2T_2  = prep + 12288;
    short* w3T2   = prep + 16384;
    short* wT0    = prep + 40960;
    short* wT1    = prep + 401408;
    short* w0T_1  = prep + 663552;
    short* w0T_2  = prep + 665600;
    short* w3T_1  = prep + 667648;
    short* lT     = prep + 692224;

    // aliases into dead radbf region (sequenced: msgp live msg2h..s2;
    // h0bb written by combine0 after s2)
    float* msgpA = ws;               // 2048*128 f
    float* msgpB = ws + 262144;      // 2048*128 f
    float* Cp    = (float*)hc1;      // 4*2048*512 f, aliases hc1 (dead after msg1)
    short* h0bb  = radbf;            // 2048*512 sh
    short* h1bb  = (short*)Y2;       // 2048*512 sh, aliases Y2 (dead)

    pre_kernel<<<GEOM_BLOCKS + PREP_BLOCKS, 256, 0, stream>>>(
        pos, cell, radbf, Y1, Y2, maskf,
        r1w0, r1w1, r1w2, r1w3, r2w0, r2w1, r2w2, r2w3,
        mw0, mw1, wemb, l0, l1, l2, prep);
    bigmlp_kernel<<<32*17, 256, 0, stream>>>(radbf,
        w0T_1, r1b0, w1T_1, r1b1, w2T_1, r1b2, hc1,
        w0T_2, r2b0, w1T_2, r2b1, w2T_2, r2b2, hc2);
    msg1_kernel<<<B_*N_, 256, 0, stream>>>(hc1, Y1, Y2, maskf, wemb, r1b3,
        w3T_1, lT, timeg, h1bf, v1, featsb);
    {
        dim3 g(B_*N_, 2);
        msg2h_kernel<<<g, 256, 0, stream>>>(hc2, Y1, maskf, w3T2, r2b3,
            h1bf, v1, msgpA, msgpB);
    }
    s2_kernel<<<B_*N_, 128, 0, stream>>>(msgpA, msgpB, mix2, featsb);
    {
        dim3 g(32, 8, 4);
        gemm_part_kernel<<<g, 256, 0, stream>>>(featsb, 704, wT0, 704, 22, 4, Cp);
        combine_kernel<<<1024, 256, 0, stream>>>(Cp, mb0, h0bb);
        gemm_part_kernel<<<g, 256, 0, stream>>>(h0bb, 512, wT1, 512, 16, 4, Cp);
        combine_kernel<<<1024, 256, 0, stream>>>(Cp, mb1, h1bb);
    }
    final3_kernel<<<B_*N_, 64, 0, stream>>>(h1bb, mw2, mb2, (float*)d_out);
}

// Round 8
// 287.428 us; speedup vs baseline: 1.0657x; 1.0657x over previous
//
#include <hip/hip_runtime.h>
#include <math.h>

#define B_ 32
#define N_ 64
#define K_ 128
#define NPAIR (B_*N_*N_)
#define NTRI 2080              // 64*65/2 pairs (i<=j) per batch
#define GEOM_BLOCKS 260        // 32*2080/256
#define PREP_COUNT 741376
#define PREP_BLOCKS 2896       // 741376/256
#define NPB 2                  // nodes per msg2b block

typedef __attribute__((ext_vector_type(8))) short short8;
typedef __attribute__((ext_vector_type(8))) __bf16 bf16x8;
typedef __attribute__((ext_vector_type(4))) float floatx4;

__device__ __forceinline__ float silu_f(float x) {
    float e = __builtin_amdgcn_exp2f(-1.442695040888963f * x);
    return x * __builtin_amdgcn_rcpf(1.0f + e);
}
__device__ __forceinline__ float4 ld4(const float* p) { return *(const float4*)p; }

__device__ __forceinline__ short f2bf(float x) {
    union { float f; unsigned u; } v; v.f = x;
    unsigned r = (v.u + 0x7FFFu + ((v.u >> 16) & 1u)) >> 16;
    return (short)r;
}
__device__ __forceinline__ float bf2f(short s) {
    union { unsigned u; float f; } v;
    v.u = ((unsigned)(unsigned short)s) << 16;
    return v.f;
}
__device__ __forceinline__ bf16x8 ld_frag(const short* p) {
    short8 r = *(const short8*)p;
    return __builtin_bit_cast(bf16x8, r);
}

// triangular decode: t in [0,2080) -> (i,j), i<=j
__device__ __forceinline__ int2 tri_decode(int t) {
    float f = (129.0f - sqrtf((float)(16641 - 8*t))) * 0.5f;
    int i = (int)f;
    int off = 64*i - (i*(i-1))/2;
    if (off > t) { i--; off = 64*i - (i*(i-1))/2; }
    else {
        int offn = 64*(i+1) - ((i+1)*i)/2;
        if (offn <= t) { i = i+1; off = offn; }
    }
    return make_int2(i, i + (t - off));
}

// ---------------------------------------------------------------------------
// pre: fused geom (triangular, hw sin/cos) + weight prep. (unchanged layout)
// ---------------------------------------------------------------------------
__global__ __launch_bounds__(256) void pre_kernel(
    const float* __restrict__ pos, const float* __restrict__ cell,
    short* __restrict__ radbf, float* __restrict__ Y1, float* __restrict__ Y2,
    float* __restrict__ maskf,
    const float* __restrict__ r1w0, const float* __restrict__ r1w1,
    const float* __restrict__ r1w2, const float* __restrict__ r1w3,
    const float* __restrict__ r2w0, const float* __restrict__ r2w1,
    const float* __restrict__ r2w2, const float* __restrict__ r2w3,
    const float* __restrict__ mw0, const float* __restrict__ mw1,
    const float* __restrict__ wemb,
    const float* __restrict__ l0, const float* __restrict__ l1,
    const float* __restrict__ l2, short* __restrict__ dst)
{
    int t = threadIdx.x;
    if (blockIdx.x < GEOM_BLOCKS) {
        int gt = blockIdx.x * 256 + t;
        int b = gt / NTRI;
        int tt = gt - b*NTRI;
        int2 ij = tri_decode(tt);
        int i = ij.x, j = ij.y;
        const float* pi = pos + (size_t)(b*N_ + i)*3;
        const float* pj = pos + (size_t)(b*N_ + j)*3;
        float d0 = pi[0]-pj[0], d1 = pi[1]-pj[1], d2 = pi[2]-pj[2];
        d0 -= rintf(d0); d1 -= rintf(d1); d2 -= rintf(d2);
        const float* C = cell + b*9;
        float dc0 = d0*C[0] + d1*C[3] + d2*C[6];
        float dc1 = d0*C[1] + d1*C[4] + d2*C[7];
        float dc2 = d0*C[2] + d1*C[5] + d2*C[8];
        float r2 = fmaxf(dc0*dc0 + dc1*dc1 + dc2*dc2, 1e-12f);
        float r = sqrtf(r2);
        bool m = (r < 5.0f) && (i != j);
        float mf = m ? 1.0f : 0.0f;
        float rs = m ? r : 1.0f;
        float inv_rs = __builtin_amdgcn_rcpf(rs);
        inv_rs = inv_rs * (2.0f - rs*inv_rs);
        float x = dc0*inv_rs*mf, y = dc1*inv_rs*mf, z = dc2*inv_rs*mf;
        float u = r * 0.2f;
        float u2 = u*u, u4 = u2*u2, u5 = u4*u;
        float fc = 1.0f - 21.0f*u5 + 35.0f*u5*u - 15.0f*u5*u2;
        fc = (u < 1.0f) ? fc : 0.0f;
        float pref = 0.6324555320336759f * inv_rs * (fc * mf);
        float rev = 0.1f * rs;
        float sw = __builtin_amdgcn_sinf(rev);
        float cw = __builtin_amdgcn_cosf(rev);
        float c2 = 2.0f * cw;
        short8 sv;
        float sp = 0.f, s = sw;
        #pragma unroll
        for (int n = 0; n < 8; n++) {
            sv[n] = f2bf(pref * s);
            float ns = c2*s - sp;
            sp = s; s = ns;
        }
        size_t pu = ((size_t)b*64 + i)*64 + j;
        size_t pl = ((size_t)b*64 + j)*64 + i;
        *(short8*)&radbf[pu*8] = sv;
        const float s3  = 1.7320508075688772f;
        const float s5  = 2.23606797749979f;
        const float s15 = 3.872983346207417f;
        float y1x = s3*x, y1y = s3*y, y1z = s3*z;
        Y1[pu*3+0] = y1x; Y1[pu*3+1] = y1y; Y1[pu*3+2] = y1z;
        Y1[pl*3+0] = -y1x; Y1[pl*3+1] = -y1y; Y1[pl*3+2] = -y1z;
        float q0 = s15*x*y, q1 = s15*y*z, q2 = 0.5f*s5*(3.0f*z*z - 1.0f);
        float q3 = s15*x*z, q4 = 0.5f*s15*(x*x - y*y);
        Y2[pu*5+0]=q0; Y2[pu*5+1]=q1; Y2[pu*5+2]=q2; Y2[pu*5+3]=q3; Y2[pu*5+4]=q4;
        Y2[pl*5+0]=q0; Y2[pl*5+1]=q1; Y2[pl*5+2]=q2; Y2[pl*5+3]=q3; Y2[pl*5+4]=q4;
        maskf[pu] = mf; maskf[pl] = mf;
        return;
    }
    int idx = (blockIdx.x - GEOM_BLOCKS) * 256 + t;
    if (idx >= PREP_COUNT) return;
    short v;
    if (idx < 4096) {
        int n = idx >> 6, k = idx & 63; v = f2bf(r1w1[k*64 + n]);
    } else if (idx < 8192) {
        int i = idx - 4096; int n = i >> 6, k = i & 63; v = f2bf(r1w2[k*64 + n]);
    } else if (idx < 12288) {
        int i = idx - 8192; int n = i >> 6, k = i & 63; v = f2bf(r2w1[k*64 + n]);
    } else if (idx < 16384) {
        int i = idx - 12288; int n = i >> 6, k = i & 63; v = f2bf(r2w2[k*64 + n]);
    } else if (idx < 40960) {
        int i = idx - 16384;
        v = (i < 16384) ? f2bf(r2w3[(i & 63)*256 + (i >> 6)]) : (short)0;
    } else if (idx < 401408) {
        int i = idx - 40960; int n = i / 704, k = i - n*704;
        v = (k < 641) ? f2bf(mw0[(size_t)k*512 + n]) : (short)0;
    } else if (idx < 663552) {
        int i = idx - 401408; int n = i >> 9, k = i & 511;
        v = f2bf(mw1[(size_t)k*512 + n]);
    } else if (idx < 665600) {
        int i = idx - 663552; int n = i >> 5, k = i & 31;
        v = (k < 8) ? f2bf(r1w0[k*64 + n]) : (short)0;
    } else if (idx < 667648) {
        int i = idx - 665600; int n = i >> 5, k = i & 31;
        v = (k < 8) ? f2bf(r2w0[k*64 + n]) : (short)0;
    } else if (idx < 692224) {
        int i = idx - 667648; int col = i >> 6, h = i & 63;
        v = f2bf(r1w3[h*384 + col] * wemb[col & 127] * 0.0625f);
    } else {
        int i = idx - 692224; int n = i / 384, k = i - n*384;
        float f;
        if (k < 128)       f = l0[k*128 + n];
        else if (k < 256)  f = l2[(k-128)*128 + n];
        else               f = l1[(k-256)*128 + n];
        v = f2bf(f);
    }
    dst[idx] = v;
}

// ---------------------------------------------------------------------------
// bigmlp: triangular pair-parallel radial MLPs; hc outputs PRE-MASKED.
// ---------------------------------------------------------------------------
__global__ __launch_bounds__(256) void bigmlp_kernel(
    const short* __restrict__ radbf, const float* __restrict__ maskg,
    const short* __restrict__ w0T1, const float* __restrict__ b01,
    const short* __restrict__ w1T1, const float* __restrict__ b11,
    const short* __restrict__ w2T1, const float* __restrict__ b21,
    short* __restrict__ hc1,
    const short* __restrict__ w0T2, const float* __restrict__ b02,
    const short* __restrict__ w1T2, const float* __restrict__ b12,
    const short* __restrict__ w2T2, const float* __restrict__ b22,
    short* __restrict__ hc2)
{
    __shared__ short radB[128*40];
    __shared__ short actA[128*72];
    __shared__ short actB[128*72];
    __shared__ int prs[128];
    __shared__ float maskv[128];
    int t = threadIdx.x;
    int wv = t >> 6, lane = t & 63, qd = lane >> 4, nn = lane & 15;
    int bb = blockIdx.x / 17;
    int chunk = blockIdx.x - bb*17;

    if (t < 128) {
        int tt0 = chunk*128 + t;
        uint4 z = {0,0,0,0};
        uint4 rv = z;
        int pr = -1;
        float mv = 0.f;
        if (tt0 < NTRI) {
            int2 ij = tri_decode(tt0);
            pr = (ij.x << 8) | ij.y;
            size_t pu = ((size_t)bb*64 + ij.x)*64 + ij.y;
            rv = *(const uint4*)&radbf[pu*8];
            mv = maskg[pu];
        }
        prs[t] = pr;
        maskv[t] = mv;
        *(uint4*)&radB[t*40]      = rv;
        *(uint4*)&radB[t*40 + 8]  = z;
        *(uint4*)&radB[t*40 + 16] = z;
        *(uint4*)&radB[t*40 + 24] = z;
        *(uint4*)&radB[t*40 + 32] = z;
    }
    __syncthreads();

    const short* w0Ts[2] = {w0T1, w0T2};
    const short* w1Ts[2] = {w1T1, w1T2};
    const short* w2Ts[2] = {w2T1, w2T2};
    const float* b0s[2]  = {b01, b02};
    const float* b1s[2]  = {b11, b12};
    const float* b2s[2]  = {b21, b22};
    short* hcs[2] = {hc1, hc2};

    for (int net = 0; net < 2; net++) {
        const short* w0T = w0Ts[net];
        const short* w1T = w1Ts[net];
        const short* w2T = w2Ts[net];
        const float* b0 = b0s[net];
        const float* b1 = b1s[net];
        const float* b2 = b2s[net];
        short* hc = hcs[net];
        #pragma unroll
        for (int ms = 0; ms < 2; ms++) {
            int r0 = wv*32 + ms*16;
            bf16x8 a = ld_frag(&radB[(r0 + nn)*40 + qd*8]);
            #pragma unroll
            for (int tt = 0; tt < 4; tt++) {
                floatx4 acc = (floatx4){0.f,0.f,0.f,0.f};
                bf16x8 bb_ = ld_frag(&w0T[(tt*16 + nn)*32 + qd*8]);
                acc = __builtin_amdgcn_mfma_f32_16x16x32_bf16(a, bb_, acc, 0, 0, 0);
                int col = tt*16 + nn;
                float bv = b0[col];
                #pragma unroll
                for (int i = 0; i < 4; i++)
                    actA[(r0 + qd*4 + i)*72 + col] = f2bf(silu_f(acc[i] + bv));
            }
        }
        __syncthreads();
        #pragma unroll
        for (int ms = 0; ms < 2; ms++) {
            int r0 = wv*32 + ms*16;
            bf16x8 a0 = ld_frag(&actA[(r0 + nn)*72 + qd*8]);
            bf16x8 a1 = ld_frag(&actA[(r0 + nn)*72 + 32 + qd*8]);
            #pragma unroll
            for (int tt = 0; tt < 4; tt++) {
                floatx4 acc = (floatx4){0.f,0.f,0.f,0.f};
                bf16x8 b0f = ld_frag(&w1T[(tt*16 + nn)*64 + qd*8]);
                bf16x8 b1f = ld_frag(&w1T[(tt*16 + nn)*64 + 32 + qd*8]);
                acc = __builtin_amdgcn_mfma_f32_16x16x32_bf16(a0, b0f, acc, 0, 0, 0);
                acc = __builtin_amdgcn_mfma_f32_16x16x32_bf16(a1, b1f, acc, 0, 0, 0);
                int col = tt*16 + nn;
                float bv = b1[col];
                #pragma unroll
                for (int i = 0; i < 4; i++)
                    actB[(r0 + qd*4 + i)*72 + col] = f2bf(silu_f(acc[i] + bv));
            }
        }
        __syncthreads();
        #pragma unroll
        for (int ms = 0; ms < 2; ms++) {
            int r0 = wv*32 + ms*16;
            bf16x8 a0 = ld_frag(&actB[(r0 + nn)*72 + qd*8]);
            bf16x8 a1 = ld_frag(&actB[(r0 + nn)*72 + 32 + qd*8]);
            #pragma unroll
            for (int tt = 0; tt < 4; tt++) {
                floatx4 acc = (floatx4){0.f,0.f,0.f,0.f};
                bf16x8 b0f = ld_frag(&w2T[(tt*16 + nn)*64 + qd*8]);
                bf16x8 b1f = ld_frag(&w2T[(tt*16 + nn)*64 + 32 + qd*8]);
                acc = __builtin_amdgcn_mfma_f32_16x16x32_bf16(a0, b0f, acc, 0, 0, 0);
                acc = __builtin_amdgcn_mfma_f32_16x16x32_bf16(a1, b1f, acc, 0, 0, 0);
                int col = tt*16 + nn;
                float bv = b2[col];
                #pragma unroll
                for (int i = 0; i < 4; i++) {
                    int ridx = r0 + qd*4 + i;
                    int pr = prs[ridx];
                    if (pr >= 0) {
                        short val = f2bf(silu_f(acc[i] + bv) * maskv[ridx]);
                        int pi = pr >> 8, pj = pr & 255;
                        size_t base = (size_t)bb*4096;
                        hc[(base + pi*64 + pj)*64 + col] = val;
                        if (pi != pj)
                            hc[(base + pj*64 + pi)*64 + col] = val;
                    }
                }
            }
        }
        __syncthreads();
    }
}

// ---------------------------------------------------------------------------
// msg1: per-node pass-1 messages (unchanged from R7; hc1 pre-mask is a no-op
// here since Ym already carries the mask).
// ---------------------------------------------------------------------------
__global__ __launch_bounds__(256) void msg1_kernel(
    const short* __restrict__ hc1, const float* __restrict__ Y1g,
    const float* __restrict__ Y2g, const float* __restrict__ maskg,
    const float* __restrict__ wemb, const float* __restrict__ b3,
    const short* __restrict__ w3T, const short* __restrict__ lT,
    const float* __restrict__ timeg,
    short* __restrict__ h1bf, float* __restrict__ v1g, short* __restrict__ featsb)
{
    __shared__ __align__(16) char pool[19008];
    short* hcT  = (short*)pool;
    short* A2   = (short*)pool;
    short* YmB  = (short*)(pool + 9216);
    short* GB   = (short*)(pool + 11520);
    float* msgF = (float*)(pool + 13824);
    float* qF   = (float*)(pool + 18432);
    float* SY   = (float*)(pool + 18944);

    int t = threadIdx.x;
    int wv = t >> 6, lane = t & 63, qd = lane >> 4, nn = lane & 15;
    int node = blockIdx.x;
    int b = node >> 6;
    size_t pbase = (size_t)node * 64;

    for (int idx = t; idx < 512; idx += 256) {
        int j = idx >> 3, h0 = (idx & 7)*8;
        short8 v = *(const short8*)&hc1[((size_t)node*64 + j)*64 + h0];
        #pragma unroll
        for (int q = 0; q < 8; q++) hcT[(h0 + q)*72 + j] = v[q];
    }
    for (int idx = t; idx < 504; idx += 256) YmB[648 + idx] = 0;
    if (t < 64) {
        int j = t;
        float mf = maskg[pbase + j];
        YmB[j] = f2bf(mf);
        #pragma unroll
        for (int m = 0; m < 3; m++) YmB[(1+m)*72 + j] = f2bf(Y1g[(pbase+j)*3 + m] * mf);
        #pragma unroll
        for (int m = 0; m < 5; m++) YmB[(4+m)*72 + j] = f2bf(Y2g[(pbase+j)*5 + m] * mf);
    }
    __syncthreads();
    if (t < 16) {
        float acc = 0.f;
        if (t < 9) for (int j = 0; j < 64; j++) acc += bf2f(YmB[t*72 + j]);
        SY[t] = acc;
    }
    {
        floatx4 accG = (floatx4){0.f,0.f,0.f,0.f};
        #pragma unroll
        for (int ks = 0; ks < 64; ks += 32) {
            bf16x8 a = ld_frag(&YmB[nn*72 + ks + qd*8]);
            bf16x8 bfr = ld_frag(&hcT[(wv*16 + nn)*72 + ks + qd*8]);
            accG = __builtin_amdgcn_mfma_f32_16x16x32_bf16(a, bfr, accG, 0, 0, 0);
        }
        #pragma unroll
        for (int i = 0; i < 4; i++)
            GB[(qd*4 + i)*72 + wv*16 + nn] = f2bf(accG[i]);
    }
    __syncthreads();
    {
        short8 z8 = {0,0,0,0,0,0,0,0};
        for (int idx = t; idx < 720; idx += 256) *(short8*)&A2[idx*8] = z8;
        bf16x8 a0f = ld_frag(&GB[nn*72 + 0  + qd*8]);
        bf16x8 a1f = ld_frag(&GB[nn*72 + 32 + qd*8]);
        #pragma unroll
        for (int tl = 0; tl < 6; tl++) {
            int col0 = (wv*6 + tl)*16;
            floatx4 acc = (floatx4){0.f,0.f,0.f,0.f};
            bf16x8 b0f = ld_frag(&w3T[(col0 + nn)*64 + 0  + qd*8]);
            bf16x8 b1f = ld_frag(&w3T[(col0 + nn)*64 + 32 + qd*8]);
            acc = __builtin_amdgcn_mfma_f32_16x16x32_bf16(a0f, b0f, acc, 0, 0, 0);
            acc = __builtin_amdgcn_mfma_f32_16x16x32_bf16(a1f, b1f, acc, 0, 0, 0);
            int col = col0 + nn;
            int csec = col >> 7, k = col & 127;
            #pragma unroll
            for (int i = 0; i < 4; i++) {
                int m = qd*4 + i;
                bool valid = (csec == 0) ? (m == 0)
                           : (csec == 1) ? (m >= 1 && m <= 3)
                                         : (m >= 4 && m <= 8);
                if (valid)
                    msgF[m*128 + k] = acc[i] + SY[m]*b3[col]*wemb[k]*0.0625f;
            }
        }
    }
    __syncthreads();
    A2[5760 + t] = 0;
    A2[6016 + t] = 0;
    if (t < 128) {
        float acc = 0.f;
        #pragma unroll
        for (int m = 4; m < 9; m++) { float v = msgF[m*128 + t]; acc += v*v; }
        qF[t] = acc;
    }
    __syncthreads();
    A2[t] = (t < 128) ? f2bf(msgF[t]) : f2bf(qF[t - 128]);
    if (t < 128) {
        #pragma unroll
        for (int m = 1; m <= 3; m++)
            A2[m*392 + 256 + t] = f2bf(msgF[m*128 + t]);
    }
    __syncthreads();
    #pragma unroll
    for (int tt = 0; tt < 2; tt++) {
        int col = (wv*2 + tt)*16 + nn;
        floatx4 acc = (floatx4){0.f,0.f,0.f,0.f};
        #pragma unroll
        for (int ks = 0; ks < 384; ks += 32) {
            bf16x8 a = ld_frag(&A2[nn*392 + ks + qd*8]);
            bf16x8 bfr = ld_frag(&lT[(size_t)col*384 + ks + qd*8]);
            acc = __builtin_amdgcn_mfma_f32_16x16x32_bf16(a, bfr, acc, 0, 0, 0);
        }
        if (qd == 0) {
            float s1 = acc[0];
            featsb[(size_t)node*704 + col] = f2bf(s1);
            h1bf[(size_t)node*128 + col] = f2bf(silu_f(s1));
            #pragma unroll
            for (int i = 1; i < 4; i++) {
                float v = acc[i];
                v1g[(size_t)node*384 + (i-1)*128 + col] = v;
                featsb[(size_t)node*704 + 128 + (i-1)*128 + col] = f2bf(v);
            }
        }
    }
    if (t == 0) featsb[(size_t)node*704 + 640] = f2bf(timeg[b]);
    if (t < 63) featsb[(size_t)node*704 + 641 + t] = 0;
}

// ---------------------------------------------------------------------------
// msg2b: NPB nodes per block, grid 32*32=1024. hc2 (PRE-MASKED) A-frags read
// directly from global; srcH/srcI mask-folded in LDS; uniform epilogue
// (acc + b3[col]) * src; no atomics; fused s2 = msgab/16 @ mix2.
// LDS 39.4 KB -> 4 blocks/CU.
// ---------------------------------------------------------------------------
__global__ __launch_bounds__(256) void msg2b_kernel(
    const short* __restrict__ hc2, const float* __restrict__ Y1g,
    const float* __restrict__ maskg, const short* __restrict__ w3T2,
    const float* __restrict__ b3, const short* __restrict__ h1bf,
    const float* __restrict__ v1g, const float* __restrict__ mix2,
    short* __restrict__ featsb)
{
    __shared__ __align__(16) char pool[39424];
    short* srcH = (short*)pool;                   // [64][136] mask-sel h1 (bf16)
    short* srcI = (short*)(pool + 17408);         // [64][136] mask*Y1*v1 (bf16)
    float* msgW = (float*)(pool + 34816);         // [4][128]
    float* y1m  = (float*)(pool + 36864);         // [2][64][4] (mask-folded Y1)
    float* mrow = (float*)(pool + 36864 + 2048);  // [2][64]

    int t = threadIdx.x;
    int wv = t >> 6, lane = t & 63, qd = lane >> 4, nn = lane & 15;
    int b = blockIdx.x >> 5;
    int ig = blockIdx.x & 31;
    int i0 = ig * NPB;

    // prolog: y1m/mrow for ii=0 into buffer 0
    if (t < 64) {
        int j = t;
        size_t pb = ((size_t)(b*64 + i0))*64 + j;
        float mf = maskg[pb];
        mrow[j] = mf;
        #pragma unroll
        for (int m = 0; m < 3; m++) y1m[j*4 + m] = Y1g[pb*3 + m] * mf;
    }
    __syncthreads();

    for (int ii = 0; ii < NPB; ii++) {
        int i = i0 + ii;
        size_t node = (size_t)b*64 + i;
        int cur = ii & 1;
        const float* y1c = y1m + cur*256;
        const float* mrc = mrow + cur*64;

        // phase A: build srcH (mask-select h1) and srcI (mask*Y1 . v1)
        for (int idx = t; idx < 2048; idx += 256) {
            int j = idx >> 5, kq = (idx & 31)*4;
            uint2 hv = *(const uint2*)&h1bf[((size_t)b*64 + j)*128 + kq];
            if (mrc[j] == 0.f) { hv.x = 0u; hv.y = 0u; }
            *(uint2*)&srcH[j*136 + kq] = hv;
            const float* vb = &v1g[((size_t)b*64 + j)*384 + kq];
            float4 vx = ld4(vb), vy = ld4(vb + 128), vz = ld4(vb + 256);
            float yx = y1c[j*4], yy = y1c[j*4+1], yz = y1c[j*4+2];
            srcI[j*136 + kq + 0] = f2bf(yx*vx.x + yy*vy.x + yz*vz.x);
            srcI[j*136 + kq + 1] = f2bf(yx*vx.y + yy*vy.y + yz*vz.y);
            srcI[j*136 + kq + 2] = f2bf(yx*vx.z + yy*vy.z + yz*vz.z);
            srcI[j*136 + kq + 3] = f2bf(yx*vx.w + yy*vy.w + yz*vz.w);
        }
        __syncthreads();

        // phase B: GEMM (A from global hc2, pre-masked) + epilogue
        {
            const short* arow = &hc2[(node*64 + (size_t)(wv*16 + nn))*64];
            bf16x8 a0 = ld_frag(arow + qd*8);
            bf16x8 a1 = ld_frag(arow + 32 + qd*8);
            #pragma unroll
            for (int tt = 0; tt < 8; tt++) {
                int col0 = tt*16 + nn;
                int col1 = col0 + 128;
                floatx4 acc0 = (floatx4){0.f,0.f,0.f,0.f};
                floatx4 acc1 = (floatx4){0.f,0.f,0.f,0.f};
                bf16x8 b00 = ld_frag(&w3T2[(size_t)col0*64 + qd*8]);
                bf16x8 b01 = ld_frag(&w3T2[(size_t)col0*64 + 32 + qd*8]);
                bf16x8 b10 = ld_frag(&w3T2[(size_t)col1*64 + qd*8]);
                bf16x8 b11 = ld_frag(&w3T2[(size_t)col1*64 + 32 + qd*8]);
                acc0 = __builtin_amdgcn_mfma_f32_16x16x32_bf16(a0, b00, acc0, 0, 0, 0);
                acc0 = __builtin_amdgcn_mfma_f32_16x16x32_bf16(a1, b01, acc0, 0, 0, 0);
                acc1 = __builtin_amdgcn_mfma_f32_16x16x32_bf16(a0, b10, acc1, 0, 0, 0);
                acc1 = __builtin_amdgcn_mfma_f32_16x16x32_bf16(a1, b11, acc1, 0, 0, 0);
                float bb0 = b3[col0], bb1 = b3[col1];
                float p = 0.f;
                #pragma unroll
                for (int i4 = 0; i4 < 4; i4++) {
                    int j = wv*16 + qd*4 + i4;
                    p += (acc0[i4] + bb0) * bf2f(srcH[j*136 + col0])
                       + (acc1[i4] + bb1) * bf2f(srcI[j*136 + col0]);
                }
                p += __shfl_xor(p, 16);
                p += __shfl_xor(p, 32);
                if (qd == 0) msgW[wv*128 + col0] = p;
            }
        }
        __syncthreads();

        // phase C: reduce msgW rows into row0; prefetch next y1m/mrow
        if (t < 128) {
            msgW[t] = msgW[t] + msgW[128 + t] + msgW[256 + t] + msgW[384 + t];
        } else if (ii + 1 < NPB) {
            int j = t - 128;
            if (j < 64) {
                size_t pb = ((size_t)(b*64 + i0 + ii + 1))*64 + j;
                float mf = maskg[pb];
                int nx = (ii + 1) & 1;
                mrow[nx*64 + j] = mf;
                #pragma unroll
                for (int m = 0; m < 3; m++)
                    y1m[nx*256 + j*4 + m] = Y1g[pb*3 + m] * mf;
            }
        }
        __syncthreads();

        // phase D: fused s2 = (msgab/16) @ mix2  (runs alongside next phase A)
        if (t < 128) {
            float acc = 0.f;
            for (int k = 0; k < 128; k++) acc += msgW[k] * mix2[k*128 + t];
            featsb[node*704 + 512 + t] = f2bf(acc * 0.0625f);
        }
        // no barrier: next phase A writes srcH/srcI (disjoint); next phase B's
        // msgW writes are fenced by the phase-A barrier.
    }
}

// ---------------------------------------------------------------------------
// gemm_part: stage-less, barrier-free split-K partial GEMM.
// ---------------------------------------------------------------------------
__global__ __launch_bounds__(256) void gemm_part_kernel(
    const short* __restrict__ A, int lda,
    const short* __restrict__ BT, int ldb,
    int ngran, int nsplit, float* __restrict__ Cp)
{
    int t = threadIdx.x;
    int wv = t >> 6, lane = t & 63, qd = lane >> 4, nn = lane & 15;
    int m0 = blockIdx.x * 64, n0 = blockIdx.y * 64, z = blockIdx.z;
    int g0 = (z*ngran)/nsplit, g1 = ((z+1)*ngran)/nsplit;
    floatx4 acc[4];
    #pragma unroll
    for (int tt = 0; tt < 4; tt++) acc[tt] = (floatx4){0.f,0.f,0.f,0.f};
    int row = wv*16 + nn;
    for (int g = g0; g < g1; g++) {
        int k = g*32;
        bf16x8 a = ld_frag(&A[(size_t)(m0 + row)*lda + k + qd*8]);
        #pragma unroll
        for (int tt = 0; tt < 4; tt++) {
            bf16x8 bb = ld_frag(&BT[(size_t)(n0 + tt*16 + nn)*ldb + k + qd*8]);
            acc[tt] = __builtin_amdgcn_mfma_f32_16x16x32_bf16(a, bb, acc[tt], 0, 0, 0);
        }
    }
    float* out = Cp + (size_t)z*2048*512;
    #pragma unroll
    for (int tt = 0; tt < 4; tt++) {
        int n = n0 + tt*16 + nn;
        #pragma unroll
        for (int i = 0; i < 4; i++)
            out[(size_t)(m0 + wv*16 + qd*4 + i)*512 + n] = acc[tt][i];
    }
}

__global__ __launch_bounds__(256) void combine_kernel(
    const float* __restrict__ Cp, const float* __restrict__ bias,
    short* __restrict__ out)
{
    int idx = (blockIdx.x * 256 + threadIdx.x) * 4;
    int n = idx & 511;
    float4 s = ld4(&Cp[idx]);
    #pragma unroll
    for (int z = 1; z < 4; z++) {
        float4 p = ld4(&Cp[(size_t)z*1048576 + idx]);
        s.x += p.x; s.y += p.y; s.z += p.z; s.w += p.w;
    }
    float4 bv = ld4(&bias[n]);
    short4 o;
    o.x = f2bf(fmaxf(s.x + bv.x, 0.f));
    o.y = f2bf(fmaxf(s.y + bv.y, 0.f));
    o.z = f2bf(fmaxf(s.z + bv.z, 0.f));
    o.w = f2bf(fmaxf(s.w + bv.w, 0.f));
    *(short4*)&out[idx] = o;
}

// final3b: fuses combine1 + final layer. h = relu(sum_z Cp + b1) in fp32.
__global__ __launch_bounds__(64) void final3b_kernel(
    const float* __restrict__ Cp, const float* __restrict__ b1,
    const float* __restrict__ w2, const float* __restrict__ b2,
    float* __restrict__ out)
{
    int node = blockIdx.x, lane = threadIdx.x;
    float a0 = 0.f, a1 = 0.f, a2 = 0.f;
    #pragma unroll
    for (int r = 0; r < 8; r++) {
        int k = r*64 + lane;
        size_t off = (size_t)node*512 + k;
        float h = Cp[off] + Cp[1048576 + off] + Cp[2*1048576 + off]
                + Cp[3*1048576 + off] + b1[k];
        h = fmaxf(h, 0.f);
        a0 += h * w2[k*3 + 0];
        a1 += h * w2[k*3 + 1];
        a2 += h * w2[k*3 + 2];
    }
    #pragma unroll
    for (int off = 32; off > 0; off >>= 1) {
        a0 += __shfl_down(a0, off);
        a1 += __shfl_down(a1, off);
        a2 += __shfl_down(a2, off);
    }
    if (lane == 0) {
        out[(size_t)node*3 + 0] = a0 + b2[0];
        out[(size_t)node*3 + 1] = a1 + b2[1];
        out[(size_t)node*3 + 2] = a2 + b2[2];
    }
}

extern "C" void kernel_launch(void* const* d_in, const int* in_sizes, int n_in,
                              void* d_out, int out_size, void* d_ws, size_t ws_size,
                              hipStream_t stream) {
    const float* pos   = (const float*)d_in[0];
    const float* timeg = (const float*)d_in[1];
    const float* cell  = (const float*)d_in[2];
    const float* wemb  = (const float*)d_in[3];
    const float* r1w0  = (const float*)d_in[4];
    const float* r1b0  = (const float*)d_in[5];
    const float* r1w1  = (const float*)d_in[6];
    const float* r1b1  = (const float*)d_in[7];
    const float* r1w2  = (const float*)d_in[8];
    const float* r1b2  = (const float*)d_in[9];
    const float* r1w3  = (const float*)d_in[10];
    const float* r1b3  = (const float*)d_in[11];
    const float* l0    = (const float*)d_in[12];
    const float* l1    = (const float*)d_in[13];
    const float* l2    = (const float*)d_in[14];
    const float* r2w0  = (const float*)d_in[15];
    const float* r2b0  = (const float*)d_in[16];
    const float* r2w1  = (const float*)d_in[17];
    const float* r2b1  = (const float*)d_in[18];
    const float* r2w2  = (const float*)d_in[19];
    const float* r2b2  = (const float*)d_in[20];
    const float* r2w3  = (const float*)d_in[21];
    const float* r2b3  = (const float*)d_in[22];
    const float* mix2  = (const float*)d_in[23];
    const float* mw0   = (const float*)d_in[24];
    const float* mb0   = (const float*)d_in[25];
    const float* mw1   = (const float*)d_in[26];
    const float* mb1   = (const float*)d_in[27];
    const float* mw2   = (const float*)d_in[28];
    const float* mb2   = (const float*)d_in[29];

    float* ws = (float*)d_ws;
    short* radbf  = (short*)ws;                          // dead after bigmlp
    float* Y1     = ws + 524288;
    float* Y2     = ws + 917504;
    float* maskf  = ws + 1572864;
    float* v1     = ws + 1703936;
    short* featsb = (short*)(ws + 2490368);
    short* prep   = (short*)(ws + 3211264);
    short* hc1    = (short*)(ws + 3590144);
    short* hc2    = (short*)(ws + 7784448);
    short* h1bf   = (short*)(ws + 11978752);

    short* w1T_1  = prep;
    short* w2T_1  = prep + 4096;
    short* w1T_2  = prep + 8192;
    short* w2T_2  = prep + 12288;
    short* w3T2   = prep + 16384;
    short* wT0    = prep + 40960;
    short* wT1    = prep + 401408;
    short* w0T_1  = prep + 663552;
    short* w0T_2  = prep + 665600;
    short* w3T_1  = prep + 667648;
    short* lT     = prep + 692224;

    float* Cp   = (float*)hc1;       // 4*2048*512 f, aliases hc1 (dead after msg1)
    short* h0bb = radbf;             // 2048*512 sh, aliases radbf (dead)

    pre_kernel<<<GEOM_BLOCKS + PREP_BLOCKS, 256, 0, stream>>>(
        pos, cell, radbf, Y1, Y2, maskf,
        r1w0, r1w1, r1w2, r1w3, r2w0, r2w1, r2w2, r2w3,
        mw0, mw1, wemb, l0, l1, l2, prep);
    bigmlp_kernel<<<32*17, 256, 0, stream>>>(radbf, maskf,
        w0T_1, r1b0, w1T_1, r1b1, w2T_1, r1b2, hc1,
        w0T_2, r2b0, w1T_2, r2b1, w2T_2, r2b2, hc2);
    msg1_kernel<<<B_*N_, 256, 0, stream>>>(hc1, Y1, Y2, maskf, wemb, r1b3,
        w3T_1, lT, timeg, h1bf, v1, featsb);
    msg2b_kernel<<<32*32, 256, 0, stream>>>(hc2, Y1, maskf, w3T2, r2b3,
        h1bf, v1, mix2, featsb);
    {
        dim3 g(32, 8, 4);
        gemm_part_kernel<<<g, 256, 0, stream>>>(featsb, 704, wT0, 704, 22, 4, Cp);
        combine_kernel<<<1024, 256, 0, stream>>>(Cp, mb0, h0bb);
        gemm_part_kernel<<<g, 256, 0, stream>>>(h0bb, 512, wT1, 512, 16, 4, Cp);
    }
    final3b_kernel<<<B_*N_, 64, 0, stream>>>(Cp, mb1, mw2, mb2, (float*)d_out);
}